// Round 12
// baseline (106.176 us; speedup 1.0000x reference)
//
#include <hip/hip_runtime.h>

typedef short   bf16x8 __attribute__((ext_vector_type(8)));
typedef float   f32x4  __attribute__((ext_vector_type(4)));

#define NVEC   131072      // 32*64*64 vectors
#define HW     4096
#define CHW    262144
#define QOFF   1
#define PERPOFF 8388609
#define ENCOFF  8388610

// ws layout: counts[512] @0, double loss @2048, float bias[512] @4096,
//            ushort wbf[512*64] @8192 (64 KB)

__device__ inline unsigned short f2bf(float f) {   // RTNE float->bf16
    unsigned int u = __float_as_uint(f);
    u += 0x7fffu + ((u >> 16) & 1u);
    return (unsigned short)(u >> 16);
}

// per code: bf16 copy of W + bias = -0.5*||w||^2 (f32-exact).
// Block 0 additionally zeroes counts + loss.
__global__ __launch_bounds__(64) void vq_prep(const float* __restrict__ wt,
                                              float* __restrict__ bias,
                                              unsigned short* __restrict__ wbf,
                                              int* __restrict__ counts,
                                              double* __restrict__ loss) {
    int c = blockIdx.x, d = threadIdx.x;
    if (c == 0) {
#pragma unroll
        for (int i = 0; i < 8; ++i) counts[d * 8 + i] = 0;
        if (d == 0) loss[0] = 0.0;
    }
    float v = wt[c * 64 + d];
    wbf[c * 64 + d] = f2bf(v);
    float s = v * v;
    for (int off = 32; off; off >>= 1) s += __shfl_down(s, off, 64);
    if (d == 0) bias[c] = -0.5f * s;
}

// 256 blocks (1/CU) x 512 threads (8 waves). Each block: 512-pos slab,
// processed as two 256-pos halves with W staged in LDS ONCE.
// Scores via mfma_f32_16x16x32_bf16 with C preloaded = -wsq/2; argmax.
// One-hot region pre-zeroed by memset; scatter of 1.0s fused here.
__global__ __launch_bounds__(512) void vq_assign(
    const float* __restrict__ x, const float* __restrict__ wt,
    const float* __restrict__ bias, const unsigned short* __restrict__ wbf,
    float* __restrict__ out, float* __restrict__ enc,
    int* __restrict__ counts, double* __restrict__ loss_acc)
{
    __shared__ unsigned short wl[512 * 64];   // 64 KB, XOR-swizzled rows
    __shared__ float  biasl[512];
    __shared__ int    hc[512];
    __shared__ int    winners[256];
    __shared__ double lred[8];

    const int t = threadIdx.x, b = blockIdx.x;
    const int batch   = b >> 3;
    const int posblk8 = (b & 7) << 9;         // 512-pos slab base

    // ---- stage W bf16 into LDS with st-swizzle (row c: byte ^= (c&7)<<4) ----
    {
        const ulonglong2* src = (const ulonglong2*)wbf;   // 16B units
#pragma unroll
        for (int i = 0; i < 8; ++i) {
            int u  = t + 512 * i;          // 16B-unit index, 0..4095
            int c  = u >> 3;               // code row
            int bo = (u & 7) << 4;         // byte-in-row
            ulonglong2 v = src[u];
            *(ulonglong2*)((char*)wl + ((c << 7) | (bo ^ ((c & 7) << 4)))) = v;
        }
        biasl[t] = bias[t];
        hc[t] = 0;
    }
    __syncthreads();

    const int wv = t >> 6, l = t & 63;
    const int g  = l >> 4, cl = l & 15;
    const int d0 = g << 3;
    const char* wlb = (const char*)wl;

    float lsAll = 0.f;

    for (int half = 0; half < 2; ++half) {
        if (half) __syncthreads();            // protect winners[] reuse
        const int posblk = posblk8 + (half << 8);
        const int posw   = posblk + (wv << 5);   // this wave's 32 pos

        // ---- load X f32 directly in A-fragment layout ----
        float xs[2][16];
        const float* xb = x + (size_t)batch * CHW + posw + cl;
#pragma unroll
        for (int s = 0; s < 2; ++s)
#pragma unroll
            for (int j = 0; j < 8; ++j) {
                xs[s][j]     = xb[(size_t)(d0 + j) * HW + 16 * s];
                xs[s][j + 8] = xb[(size_t)(32 + d0 + j) * HW + 16 * s];
            }

        bf16x8 af[2][2];
#pragma unroll
        for (int s = 0; s < 2; ++s)
#pragma unroll
            for (int h = 0; h < 2; ++h)
#pragma unroll
                for (int i = 0; i < 8; ++i)
                    af[s][h][i] = (short)f2bf(xs[s][8 * h + i]);

        // ---- score loop: 32 col-tiles of 16 codes ----
        float best[2][4]; int bidx[2][4];
#pragma unroll
        for (int s = 0; s < 2; ++s)
#pragma unroll
            for (int i = 0; i < 4; ++i) { best[s][i] = -1e30f; bidx[s][i] = 0; }

#pragma unroll 4
        for (int tt = 0; tt < 32; ++tt) {
            int c  = (tt << 4) + cl;
            int rb = c << 7;
            int sw = (c & 7) << 4;
            bf16x8 b0 = *(const bf16x8*)(wlb + (rb | ((16 * g) ^ sw)));
            bf16x8 b1 = *(const bf16x8*)(wlb + (rb | ((64 + 16 * g) ^ sw)));
            float bs = biasl[c];
#pragma unroll
            for (int s = 0; s < 2; ++s) {
                f32x4 acc = {bs, bs, bs, bs};
                acc = __builtin_amdgcn_mfma_f32_16x16x32_bf16(af[s][0], b0, acc, 0, 0, 0);
                acc = __builtin_amdgcn_mfma_f32_16x16x32_bf16(af[s][1], b1, acc, 0, 0, 0);
#pragma unroll
                for (int i = 0; i < 4; ++i)
                    if (acc[i] > best[s][i]) { best[s][i] = acc[i]; bidx[s][i] = c; }
            }
        }

        // ---- 16-lane butterfly argmax (tie -> smaller index) ----
#pragma unroll
        for (int s = 0; s < 2; ++s)
#pragma unroll
            for (int i = 0; i < 4; ++i) {
                float bd = best[s][i]; int bi = bidx[s][i];
#pragma unroll
                for (int off = 1; off < 16; off <<= 1) {
                    float od = __shfl_xor(bd, off, 64);
                    int   oi = __shfl_xor(bi, off, 64);
                    if (od > bd || (od == bd && oi < bi)) { bd = od; bi = oi; }
                }
                bidx[s][i] = bi;
            }

        // winners to LDS (row-in-wave = 16s + 4g + i), + histogram
        if (cl == 0) {
#pragma unroll
            for (int s = 0; s < 2; ++s)
#pragma unroll
                for (int i = 0; i < 4; ++i) {
                    int w = bidx[s][i];
                    winners[(wv << 5) + (s << 4) + (g << 2) + i] = w;
                    atomicAdd(&hc[w], 1);
                }
        }
        __syncthreads();

        // ---- epilogue: quantized_st + loss (f32-exact) ----
        float* outb = out + QOFF + (size_t)batch * CHW + posw + cl;
#pragma unroll
        for (int s = 0; s < 2; ++s) {
            int widx = winners[(wv << 5) + (s << 4) + cl];
            float q[16];
            *(float4*)&q[0]  = *(const float4*)(wt + widx * 64 + d0);
            *(float4*)&q[4]  = *(const float4*)(wt + widx * 64 + d0 + 4);
            *(float4*)&q[8]  = *(const float4*)(wt + widx * 64 + 32 + d0);
            *(float4*)&q[12] = *(const float4*)(wt + widx * 64 + 32 + d0 + 4);
#pragma unroll
            for (int j = 0; j < 8; ++j) {
                float da = q[j]     - xs[s][j];
                float db = q[j + 8] - xs[s][j + 8];
                lsAll += da * da + db * db;
                outb[(size_t)(d0 + j) * HW + 16 * s]      = xs[s][j]     + da;
                outb[(size_t)(32 + d0 + j) * HW + 16 * s] = xs[s][j + 8] + db;
            }
        }

        // one-hot scatter: one 1.0f per row (region pre-zeroed by memset)
        if (t < 256) {
            int widx = winners[t];
            size_t row = (size_t)batch * 4096 + posblk + t;
            enc[row * 512 + widx] = 1.0f;
        }
    }

    // ---- loss reduction (once, both halves) ----
    double lsd = (double)lsAll;
    for (int off = 32; off; off >>= 1) lsd += __shfl_down(lsd, off, 64);
    if (l == 0) lred[wv] = lsd;
    __syncthreads();
    if (t == 0) {
        double s = 0.0;
#pragma unroll
        for (int i = 0; i < 8; ++i) s += lred[i];
        atomicAdd(loss_acc, s);
    }

    int v0 = hc[t];
    if (v0) atomicAdd(&counts[t], v0);
}

__global__ __launch_bounds__(512) void vq_fin(const int* __restrict__ counts,
                                              const double* __restrict__ loss_acc,
                                              float* __restrict__ out) {
    __shared__ double red[512];
    int k = threadIdx.x;
    double p = (double)counts[k] * (1.0 / 131072.0);
    red[k] = p * log(p + 1e-10);
    __syncthreads();
    for (int s = 256; s; s >>= 1) {
        if (k < s) red[k] += red[k + s];
        __syncthreads();
    }
    if (k == 0) {
        out[PERPOFF] = (float)exp(-red[0]);
        out[0] = (float)(loss_acc[0] * 1.25 / 8388608.0);
    }
}

extern "C" void kernel_launch(void* const* d_in, const int* in_sizes, int n_in,
                              void* d_out, int out_size, void* d_ws, size_t ws_size,
                              hipStream_t stream) {
    const float* x  = (const float*)d_in[0];
    const float* wt = (const float*)d_in[1];
    float* out = (float*)d_out;
    char* ws = (char*)d_ws;

    int*            counts = (int*)ws;
    double*         loss   = (double*)(ws + 2048);
    float*          bias   = (float*)(ws + 4096);
    unsigned short* wbf    = (unsigned short*)(ws + 8192);
    float*          enc    = out + ENCOFF;

    vq_prep<<<512, 64, 0, stream>>>(wt, bias, wbf, counts, loss);
    // zero the one-hot region (268435456 B); assign scatters the 1.0s
    hipMemsetAsync((void*)enc, 0, (size_t)NVEC * 512 * sizeof(float), stream);
    vq_assign<<<256, 512, 0, stream>>>(x, wt, bias, wbf, out, enc, counts, loss);
    vq_fin<<<1, 512, 0, stream>>>(counts, loss, out);
}

// Round 13
// 95.388 us; speedup vs baseline: 1.1131x; 1.1131x over previous
//
#include <hip/hip_runtime.h>

typedef short   bf16x8 __attribute__((ext_vector_type(8)));
typedef float   f32x4  __attribute__((ext_vector_type(4)));

#define NVEC   131072      // 32*64*64 vectors
#define HW     4096
#define CHW    262144
#define QOFF   1
#define PERPOFF 8388609
#define ENCOFF  8388610

// ws layout: counts[512] @0, int ticket @2048, double loss @2056,
//            float bias[512] @4096, ushort wbf[512*64] @8192 (64 KB)

__device__ inline unsigned short f2bf(float f) {   // RTNE float->bf16
    unsigned int u = __float_as_uint(f);
    u += 0x7fffu + ((u >> 16) & 1u);
    return (unsigned short)(u >> 16);
}

// per code: bf16 copy of W + bias = -0.5*||w||^2 (f32-exact).
// Block 0 additionally zeroes counts + ticket + loss.
__global__ __launch_bounds__(64) void vq_prep(const float* __restrict__ wt,
                                              float* __restrict__ bias,
                                              unsigned short* __restrict__ wbf,
                                              int* __restrict__ counts,
                                              int* __restrict__ ticket,
                                              double* __restrict__ loss) {
    int c = blockIdx.x, d = threadIdx.x;
    if (c == 0) {
#pragma unroll
        for (int i = 0; i < 8; ++i) counts[d * 8 + i] = 0;
        if (d == 0) { loss[0] = 0.0; ticket[0] = 0; }
    }
    float v = wt[c * 64 + d];
    wbf[c * 64 + d] = f2bf(v);
    float s = v * v;
    for (int off = 32; off; off >>= 1) s += __shfl_down(s, off, 64);
    if (d == 0) bias[c] = -0.5f * s;
}

// 512 blocks x 512 threads (8 waves). Wave handles 32 rows: 2 row-sets of 16.
// Scores via mfma_f32_16x16x32_bf16 with C preloaded = -wsq/2; argmax.
// One-hot region pre-zeroed by memset; scatter of 1.0s fused here.
// Last block (ticket) computes loss/perplexity (fin folded in).
__global__ __launch_bounds__(512) void vq_assign(
    const float* __restrict__ x, const float* __restrict__ wt,
    const float* __restrict__ bias, const unsigned short* __restrict__ wbf,
    float* __restrict__ out, float* __restrict__ enc,
    int* __restrict__ counts, int* __restrict__ ticket,
    double* __restrict__ loss_acc)
{
    __shared__ unsigned short wl[512 * 64];   // 64 KB, XOR-swizzled rows
    __shared__ float  biasl[512];
    __shared__ int    hc[512];
    __shared__ int    winners[256];
    __shared__ double lred[8];
    __shared__ int    isLast;

    const int t = threadIdx.x, b = blockIdx.x;
    const int batch  = b >> 4;
    const int posblk = (b & 15) << 8;

    // ---- stage W bf16 into LDS with st-swizzle (row c: byte ^= (c&7)<<4) ----
    {
        const ulonglong2* src = (const ulonglong2*)wbf;   // 16B units
#pragma unroll
        for (int i = 0; i < 8; ++i) {
            int u  = t + 512 * i;          // 16B-unit index, 0..4095
            int c  = u >> 3;               // code row
            int bo = (u & 7) << 4;         // byte-in-row
            ulonglong2 v = src[u];
            *(ulonglong2*)((char*)wl + ((c << 7) | (bo ^ ((c & 7) << 4)))) = v;
        }
        biasl[t] = bias[t];
        hc[t] = 0;
    }
    __syncthreads();

    const int wv = t >> 6, l = t & 63;
    const int g  = l >> 4, cl = l & 15;
    const int posw = posblk + (wv << 5);      // this wave's 32 pos
    const int d0 = g << 3;

    // ---- load X f32 directly in A-fragment layout ----
    float xs[2][16];
    const float* xb = x + (size_t)batch * CHW + posw + cl;
#pragma unroll
    for (int s = 0; s < 2; ++s)
#pragma unroll
        for (int j = 0; j < 8; ++j) {
            xs[s][j]     = xb[(size_t)(d0 + j) * HW + 16 * s];
            xs[s][j + 8] = xb[(size_t)(32 + d0 + j) * HW + 16 * s];
        }

    bf16x8 af[2][2];
#pragma unroll
    for (int s = 0; s < 2; ++s)
#pragma unroll
        for (int h = 0; h < 2; ++h)
#pragma unroll
            for (int i = 0; i < 8; ++i)
                af[s][h][i] = (short)f2bf(xs[s][8 * h + i]);

    // ---- score loop: 32 col-tiles of 16 codes ----
    float best[2][4]; int bidx[2][4];
#pragma unroll
    for (int s = 0; s < 2; ++s)
#pragma unroll
        for (int i = 0; i < 4; ++i) { best[s][i] = -1e30f; bidx[s][i] = 0; }

    const char* wlb = (const char*)wl;
#pragma unroll 4
    for (int tt = 0; tt < 32; ++tt) {
        int c  = (tt << 4) + cl;
        int rb = c << 7;
        int sw = (c & 7) << 4;
        bf16x8 b0 = *(const bf16x8*)(wlb + (rb | ((16 * g) ^ sw)));
        bf16x8 b1 = *(const bf16x8*)(wlb + (rb | ((64 + 16 * g) ^ sw)));
        float bs = biasl[c];
#pragma unroll
        for (int s = 0; s < 2; ++s) {
            f32x4 acc = {bs, bs, bs, bs};
            acc = __builtin_amdgcn_mfma_f32_16x16x32_bf16(af[s][0], b0, acc, 0, 0, 0);
            acc = __builtin_amdgcn_mfma_f32_16x16x32_bf16(af[s][1], b1, acc, 0, 0, 0);
#pragma unroll
            for (int i = 0; i < 4; ++i)
                if (acc[i] > best[s][i]) { best[s][i] = acc[i]; bidx[s][i] = c; }
        }
    }

    // ---- 16-lane butterfly argmax (tie -> smaller index) ----
#pragma unroll
    for (int s = 0; s < 2; ++s)
#pragma unroll
        for (int i = 0; i < 4; ++i) {
            float bd = best[s][i]; int bi = bidx[s][i];
#pragma unroll
            for (int off = 1; off < 16; off <<= 1) {
                float od = __shfl_xor(bd, off, 64);
                int   oi = __shfl_xor(bi, off, 64);
                if (od > bd || (od == bd && oi < bi)) { bd = od; bi = oi; }
            }
            bidx[s][i] = bi;
        }

    // winners to LDS (row-in-wave = 16s + 4g + i), + histogram
    if (cl == 0) {
#pragma unroll
        for (int s = 0; s < 2; ++s)
#pragma unroll
            for (int i = 0; i < 4; ++i) {
                int w = bidx[s][i];
                winners[(wv << 5) + (s << 4) + (g << 2) + i] = w;
                atomicAdd(&hc[w], 1);
            }
    }
    __syncthreads();

    // ---- epilogue: quantized_st + loss (f32-exact) ----
    float* outb = out + QOFF + (size_t)batch * CHW + posw + cl;
    float ls = 0.f;
#pragma unroll
    for (int s = 0; s < 2; ++s) {
        int widx = winners[(wv << 5) + (s << 4) + cl];
        float q[16];
        *(float4*)&q[0]  = *(const float4*)(wt + widx * 64 + d0);
        *(float4*)&q[4]  = *(const float4*)(wt + widx * 64 + d0 + 4);
        *(float4*)&q[8]  = *(const float4*)(wt + widx * 64 + 32 + d0);
        *(float4*)&q[12] = *(const float4*)(wt + widx * 64 + 32 + d0 + 4);
#pragma unroll
        for (int j = 0; j < 8; ++j) {
            float da = q[j]     - xs[s][j];
            float db = q[j + 8] - xs[s][j + 8];
            ls += da * da + db * db;
            outb[(size_t)(d0 + j) * HW + 16 * s]      = xs[s][j]     + da;
            outb[(size_t)(32 + d0 + j) * HW + 16 * s] = xs[s][j + 8] + db;
        }
    }

    // one-hot scatter: one 1.0f per row (region pre-zeroed by memset)
    if (t < 256) {
        int widx = winners[t];
        size_t row = (size_t)batch * 4096 + posblk + t;
        enc[row * 512 + widx] = 1.0f;
    }

    // ---- loss reduction ----
    double lsd = (double)ls;
    for (int off = 32; off; off >>= 1) lsd += __shfl_down(lsd, off, 64);
    if (l == 0) lred[wv] = lsd;
    __syncthreads();
    if (t == 0) {
        double s = 0.0;
#pragma unroll
        for (int i = 0; i < 8; ++i) s += lred[i];
        atomicAdd(loss_acc, s);
    }
    int v0 = hc[t];
    if (v0) atomicAdd(&counts[t], v0);

    // ---- fin fold: last block computes loss/perplexity ----
    // __syncthreads drains vmcnt(0) -> this block's atomics are complete.
    __syncthreads();
    if (t == 0) isLast = (atomicAdd(ticket, 1) == 511);
    __syncthreads();
    if (isLast) {
        double* red = (double*)wl;        // reuse dead W tile (needs 4 KB)
        int cnt = atomicAdd(&counts[t], 0);           // L2-coherent read
        double p = (double)cnt * (1.0 / 131072.0);
        red[t] = p * log(p + 1e-10);
        __syncthreads();
        for (int s = 256; s; s >>= 1) {
            if (t < s) red[t] += red[t + s];
            __syncthreads();
        }
        if (t == 0) {
            double lt = atomicAdd(loss_acc, 0.0);     // L2-coherent read
            out[PERPOFF] = (float)exp(-red[0]);
            out[0] = (float)(lt * 1.25 / 8388608.0);
        }
    }
}

extern "C" void kernel_launch(void* const* d_in, const int* in_sizes, int n_in,
                              void* d_out, int out_size, void* d_ws, size_t ws_size,
                              hipStream_t stream) {
    const float* x  = (const float*)d_in[0];
    const float* wt = (const float*)d_in[1];
    float* out = (float*)d_out;
    char* ws = (char*)d_ws;

    int*            counts = (int*)ws;
    int*            ticket = (int*)(ws + 2048);
    double*         loss   = (double*)(ws + 2056);
    float*          bias   = (float*)(ws + 4096);
    unsigned short* wbf    = (unsigned short*)(ws + 8192);
    float*          enc    = out + ENCOFF;

    vq_prep<<<512, 64, 0, stream>>>(wt, bias, wbf, counts, ticket, loss);
    // zero the one-hot region (268435456 B); assign scatters the 1.0s
    hipMemsetAsync((void*)enc, 0, (size_t)NVEC * 512 * sizeof(float), stream);
    vq_assign<<<512, 512, 0, stream>>>(x, wt, bias, wbf, out, enc, counts, ticket, loss);
}

// Round 14
// 91.418 us; speedup vs baseline: 1.1614x; 1.0434x over previous
//
#include <hip/hip_runtime.h>

typedef short   bf16x8 __attribute__((ext_vector_type(8)));
typedef float   f32x4  __attribute__((ext_vector_type(4)));

#define NVEC   131072      // 32*64*64 vectors
#define HW     4096
#define CHW    262144
#define QOFF   1
#define PERPOFF 8388609
#define ENCOFF  8388610

// ws layout: counts[512] @0, double loss @2048, float bias[512] @4096,
//            ushort wbf[512*64] @8192 (64 KB)

__device__ inline unsigned short f2bf(float f) {   // RTNE float->bf16 (W only)
    unsigned int u = __float_as_uint(f);
    u += 0x7fffu + ((u >> 16) & 1u);
    return (unsigned short)(u >> 16);
}

// per code: bf16 copy of W + bias = 4 - 0.5*||w||^2 (positive-score shift:
// |x.w| <= 64*max|x|/512 << 4, so scores stay in ~[3.9,4.1] > 0).
__global__ __launch_bounds__(64) void vq_prep(const float* __restrict__ wt,
                                              float* __restrict__ bias,
                                              unsigned short* __restrict__ wbf,
                                              int* __restrict__ counts,
                                              double* __restrict__ loss) {
    int c = blockIdx.x, d = threadIdx.x;
    if (c == 0) {
#pragma unroll
        for (int i = 0; i < 8; ++i) counts[d * 8 + i] = 0;
        if (d == 0) loss[0] = 0.0;
    }
    float v = wt[c * 64 + d];
    wbf[c * 64 + d] = f2bf(v);
    float s = v * v;
    for (int off = 32; off; off >>= 1) s += __shfl_down(s, off, 64);
    if (d == 0) bias[c] = 4.0f - 0.5f * s;
}

// 512 blocks x 512 threads (8 waves), 2 blocks/CU (16 waves/CU, no spill).
// x kept as trunc-hi16 (= MFMA A-frag) + packed low16; exact reconstruction
// in epilogue. Argmax via positive-score ord-encoding (score|511-c), u32 max.
__global__ __launch_bounds__(512, 4) void vq_assign(
    const float* __restrict__ x, const float* __restrict__ wt,
    const float* __restrict__ bias, const unsigned short* __restrict__ wbf,
    float* __restrict__ out, float* __restrict__ enc,
    int* __restrict__ counts, double* __restrict__ loss_acc)
{
    __shared__ unsigned short wl[512 * 64];   // 64 KB, XOR-swizzled rows
    __shared__ float  biasl[512];
    __shared__ int    hc[512];
    __shared__ int    winners[256];
    __shared__ double lred[8];

    const int t = threadIdx.x, b = blockIdx.x;
    const int batch  = b >> 4;
    const int posblk = (b & 15) << 8;

    // ---- stage W bf16 into LDS with st-swizzle (row c: byte ^= (c&7)<<4) ----
    {
        const ulonglong2* src = (const ulonglong2*)wbf;   // 16B units
#pragma unroll
        for (int i = 0; i < 8; ++i) {
            int u  = t + 512 * i;          // 16B-unit index, 0..4095
            int c  = u >> 3;               // code row
            int bo = (u & 7) << 4;         // byte-in-row
            ulonglong2 v = src[u];
            *(ulonglong2*)((char*)wl + ((c << 7) | (bo ^ ((c & 7) << 4)))) = v;
        }
        biasl[t] = bias[t];
        hc[t] = 0;
    }
    __syncthreads();

    const int wv = t >> 6, l = t & 63;
    const int g  = l >> 4, cl = l & 15;
    const int posw = posblk + (wv << 5);      // this wave's 32 pos
    const int d0 = g << 3;

    // ---- load X, pack hi16 (A-frag, truncated bf16) + lo16 (exact residual) ----
    union AFU { unsigned u[4]; bf16x8 v; };
    AFU af[2][2]; unsigned lo[2][2][4];
    const float* xb = x + (size_t)batch * CHW + posw + cl;
#pragma unroll
    for (int s = 0; s < 2; ++s)
#pragma unroll
        for (int h = 0; h < 2; ++h) {
            int dbase = (h ? 32 : 0) + d0;
#pragma unroll
            for (int k = 0; k < 4; ++k) {
                unsigned u0 = __float_as_uint(xb[(size_t)(dbase + 2 * k)     * HW + 16 * s]);
                unsigned u1 = __float_as_uint(xb[(size_t)(dbase + 2 * k + 1) * HW + 16 * s]);
                af[s][h].u[k] = (u1 & 0xffff0000u) | (u0 >> 16);
                lo[s][h][k]   = (u1 << 16)         | (u0 & 0xffffu);
            }
        }

    // ---- score loop: 32 col-tiles of 16 codes; ord-encoded argmax ----
    unsigned best[2][4];
#pragma unroll
    for (int s = 0; s < 2; ++s)
#pragma unroll
        for (int i = 0; i < 4; ++i) best[s][i] = 0u;

    const char* wlb = (const char*)wl;
#pragma unroll 4
    for (int tt = 0; tt < 32; ++tt) {
        int c  = (tt << 4) + cl;
        int rb = c << 7;
        int sw = (c & 7) << 4;
        bf16x8 b0 = *(const bf16x8*)(wlb + (rb | ((16 * g) ^ sw)));
        bf16x8 b1 = *(const bf16x8*)(wlb + (rb | ((64 + 16 * g) ^ sw)));
        float bs = biasl[c];
        unsigned tag = 511u - (unsigned)c;
#pragma unroll
        for (int s = 0; s < 2; ++s) {
            f32x4 acc = {bs, bs, bs, bs};
            acc = __builtin_amdgcn_mfma_f32_16x16x32_bf16(af[s][0].v, b0, acc, 0, 0, 0);
            acc = __builtin_amdgcn_mfma_f32_16x16x32_bf16(af[s][1].v, b1, acc, 0, 0, 0);
#pragma unroll
            for (int i = 0; i < 4; ++i) {
                unsigned e = (__float_as_uint(acc[i]) & ~511u) | tag;
                if (e > best[s][i]) best[s][i] = e;
            }
        }
    }

    // ---- 16-lane butterfly max (u32; tie -> larger tag = smaller index) ----
#pragma unroll
    for (int s = 0; s < 2; ++s)
#pragma unroll
        for (int i = 0; i < 4; ++i) {
            unsigned bd = best[s][i];
#pragma unroll
            for (int off = 1; off < 16; off <<= 1) {
                unsigned od = (unsigned)__shfl_xor((int)bd, off, 64);
                if (od > bd) bd = od;
            }
            best[s][i] = bd;
        }

    // winners to LDS (row-in-wave = 16s + 4g + i), + histogram
    if (cl == 0) {
#pragma unroll
        for (int s = 0; s < 2; ++s)
#pragma unroll
            for (int i = 0; i < 4; ++i) {
                int w = 511 - (int)(best[s][i] & 511u);
                winners[(wv << 5) + (s << 4) + (g << 2) + i] = w;
                atomicAdd(&hc[w], 1);
            }
    }
    __syncthreads();

    // ---- epilogue: reconstruct exact x, quantized_st + loss (f32-exact) ----
    float* outb = out + QOFF + (size_t)batch * CHW + posw + cl;
    float ls = 0.f;
#pragma unroll
    for (int s = 0; s < 2; ++s) {
        int widx = winners[(wv << 5) + (s << 4) + cl];
#pragma unroll
        for (int h = 0; h < 2; ++h) {
            int dbase = (h ? 32 : 0) + d0;
            float qarr[8];
            *(float4*)&qarr[0] = *(const float4*)(wt + widx * 64 + dbase);
            *(float4*)&qarr[4] = *(const float4*)(wt + widx * 64 + dbase + 4);
#pragma unroll
            for (int k = 0; k < 4; ++k) {
                unsigned a = af[s][h].u[k], ld = lo[s][h][k];
                float x0 = __uint_as_float(((a & 0xffffu) << 16) | (ld & 0xffffu));
                float x1 = __uint_as_float((a & 0xffff0000u)     | (ld >> 16));
                float da = qarr[2 * k]     - x0;
                float db = qarr[2 * k + 1] - x1;
                ls += da * da + db * db;
                outb[(size_t)(dbase + 2 * k)     * HW + 16 * s] = x0 + da;
                outb[(size_t)(dbase + 2 * k + 1) * HW + 16 * s] = x1 + db;
            }
        }
    }

    // one-hot scatter: one 1.0f per row (region pre-zeroed by memset)
    if (t < 256) {
        int widx = winners[t];
        size_t row = (size_t)batch * 4096 + posblk + t;
        enc[row * 512 + widx] = 1.0f;
    }

    // ---- loss reduction ----
    double lsd = (double)ls;
    for (int off = 32; off; off >>= 1) lsd += __shfl_down(lsd, off, 64);
    if (l == 0) lred[wv] = lsd;
    __syncthreads();
    if (t == 0) {
        double s = 0.0;
#pragma unroll
        for (int i = 0; i < 8; ++i) s += lred[i];
        atomicAdd(loss_acc, s);
    }

    int v0 = hc[t];
    if (v0) atomicAdd(&counts[t], v0);
}

__global__ __launch_bounds__(512) void vq_fin(const int* __restrict__ counts,
                                              const double* __restrict__ loss_acc,
                                              float* __restrict__ out) {
    __shared__ double red[512];
    int k = threadIdx.x;
    double p = (double)counts[k] * (1.0 / 131072.0);
    red[k] = p * log(p + 1e-10);
    __syncthreads();
    for (int s = 256; s; s >>= 1) {
        if (k < s) red[k] += red[k + s];
        __syncthreads();
    }
    if (k == 0) {
        out[PERPOFF] = (float)exp(-red[0]);
        out[0] = (float)(loss_acc[0] * 1.25 / 8388608.0);
    }
}

extern "C" void kernel_launch(void* const* d_in, const int* in_sizes, int n_in,
                              void* d_out, int out_size, void* d_ws, size_t ws_size,
                              hipStream_t stream) {
    const float* x  = (const float*)d_in[0];
    const float* wt = (const float*)d_in[1];
    float* out = (float*)d_out;
    char* ws = (char*)d_ws;

    int*            counts = (int*)ws;
    double*         loss   = (double*)(ws + 2048);
    float*          bias   = (float*)(ws + 4096);
    unsigned short* wbf    = (unsigned short*)(ws + 8192);
    float*          enc    = out + ENCOFF;

    vq_prep<<<512, 64, 0, stream>>>(wt, bias, wbf, counts, loss);
    // zero the one-hot region (268435456 B); assign scatters the 1.0s
    hipMemsetAsync((void*)enc, 0, (size_t)NVEC * 512 * sizeof(float), stream);
    vq_assign<<<512, 512, 0, stream>>>(x, wt, bias, wbf, out, enc, counts, loss);
    vq_fin<<<1, 512, 0, stream>>>(counts, loss, out);
}